// Round 1
// baseline (976.543 us; speedup 1.0000x reference)
//
#include <hip/hip_runtime.h>
#include <math.h>

#define NN 50000
#define NE 1600000
#define NG 256
#define DIN 128
#define D1 100
#define D2 20
#define DSELF 64

// ---------------- CSR build ----------------

__global__ void k_deg(const int* __restrict__ dst, int* __restrict__ deg) {
    int i = blockIdx.x * 256 + threadIdx.x;
    if (i < NE) atomicAdd(&deg[dst[i]], 1);
}

// single-block exclusive scan of deg[0..NN) -> row_start[0..NN]
__global__ void k_scan(const int* __restrict__ deg, int* __restrict__ row_start) {
    __shared__ int buf[1024];
    __shared__ int carry_s;
    int tid = threadIdx.x;
    if (tid == 0) carry_s = 0;
    __syncthreads();
    for (int base = 0; base < NN; base += 1024) {
        int i = base + tid;
        int v = (i < NN) ? deg[i] : 0;
        buf[tid] = v;
        __syncthreads();
        for (int off = 1; off < 1024; off <<= 1) {
            int t = (tid >= off) ? buf[tid - off] : 0;
            __syncthreads();
            buf[tid] += t;
            __syncthreads();
        }
        if (i < NN) row_start[i] = carry_s + buf[tid] - v;  // exclusive
        int tot = buf[1023];
        __syncthreads();
        if (tid == 0) carry_s += tot;
        __syncthreads();
    }
    if (tid == 0) row_start[NN] = carry_s;
}

__global__ void k_fill(const int* __restrict__ src, const int* __restrict__ dst,
                       const int* __restrict__ row_start, int* __restrict__ cursor,
                       int* __restrict__ csr) {
    int e = blockIdx.x * 256 + threadIdx.x;
    if (e < NE) {
        int d = dst[e];
        int p = atomicAdd(&cursor[d], 1);
        csr[row_start[d] + p] = src[e];
    }
}

// ---------------- layer GEMMs (fp32 VALU; tiny FLOP count) ----------------

// y1[n][j] = sum_k feat[n][k] * W1[k][j]   (no bias; bias added post-aggregation)
__global__ void k_gemm1(const float* __restrict__ feat, const float* __restrict__ W1,
                        float* __restrict__ y1) {
    int tid = threadIdx.x;
    int jg = tid & 31;              // 4-wide j group; 25 active of 32
    int n = blockIdx.x * 8 + (tid >> 5);
    if (jg >= 25) return;
    const float* frow = feat + (size_t)n * DIN;
    const float* w = W1 + jg * 4;
    float4 acc = make_float4(0.f, 0.f, 0.f, 0.f);
#pragma unroll 4
    for (int k = 0; k < DIN; k++) {
        float f = frow[k];
        float4 wv = *reinterpret_cast<const float4*>(w + (size_t)k * D1);
        acc.x += f * wv.x; acc.y += f * wv.y; acc.z += f * wv.z; acc.w += f * wv.w;
    }
    *reinterpret_cast<float4*>(y1 + (size_t)n * D1 + jg * 4) = acc;
}

// h1[n][d] = relu( (deg>0 ? mean y1[nbr][d] : y1[n][d]) + b1[d] )
__global__ void k_agg1(const float* __restrict__ y1, const int* __restrict__ csr,
                       const int* __restrict__ row_start, const float* __restrict__ b1,
                       float* __restrict__ h1) {
    int tid = threadIdx.x;
    int d = tid & 127;                       // 100 active of 128
    int n = blockIdx.x * 2 + (tid >> 7);
    int s = row_start[n], e = row_start[n + 1];
    if (d < D1) {
        float acc = 0.f;
        for (int i = s; i < e; i++) {
            int sn = csr[i];
            acc += y1[(size_t)sn * D1 + d];
        }
        float r = (e > s) ? acc / (float)(e - s) : y1[(size_t)n * D1 + d];
        r += b1[d];
        h1[(size_t)n * D1 + d] = fmaxf(r, 0.f);
    }
}

// y2[n][j] = sum_k h1[n][k] * W2[k][j]
__global__ void k_gemm2(const float* __restrict__ h1, const float* __restrict__ W2,
                        float* __restrict__ y2) {
    int tid = threadIdx.x;
    int j = tid & 31;                        // 20 active of 32
    int n = blockIdx.x * 8 + (tid >> 5);
    if (j >= D2) return;
    const float* hrow = h1 + (size_t)n * D1;
    float acc = 0.f;
#pragma unroll 4
    for (int k = 0; k < D1; k++) acc += hrow[k] * W2[k * D2 + j];
    y2[(size_t)n * D2 + j] = acc;
}

// h2 = relu((deg>0 ? mean y2[nbr] : y2[n]) + b2); fused per-graph pooled sum + count
__global__ void k_agg2(const float* __restrict__ y2, const int* __restrict__ csr,
                       const int* __restrict__ row_start, const float* __restrict__ b2,
                       const int* __restrict__ gid,
                       float* __restrict__ hg_sum, float* __restrict__ cnt) {
    int tid = threadIdx.x;
    int j = tid & 31;                        // 20 active of 32
    int n = blockIdx.x * 8 + (tid >> 5);
    int s = row_start[n], e = row_start[n + 1];
    int g = gid[n];
    if (j < D2) {
        float acc = 0.f;
        for (int i = s; i < e; i++) {
            int sn = csr[i];
            acc += y2[(size_t)sn * D2 + j];
        }
        float r = (e > s) ? acc / (float)(e - s) : y2[(size_t)n * D2 + j];
        r = fmaxf(r + b2[j], 0.f);
        atomicAdd(&hg_sum[g * D2 + j], r);
    }
    if (j == 0) atomicAdd(&cnt[g], 1.f);
}

// per-graph: mean-pool finalize, z_proj, bilinear gate, 20->10->1 MLP
__global__ void k_final(const float* __restrict__ hg_sum, const float* __restrict__ cnt,
                        const float* __restrict__ self_feat,
                        const float* __restrict__ Wp, const float* __restrict__ bp,
                        const float* __restrict__ Wf1, const float* __restrict__ bf1,
                        const float* __restrict__ Wf2, const float* __restrict__ bf2,
                        float* __restrict__ out) {
    int g = blockIdx.x * blockDim.x + threadIdx.x;
    if (g >= NG) return;
    float inv = 1.f / fmaxf(cnt[g], 1.f);
    const float* sf = self_feat + g * DSELF;
    float f[D2];
    for (int j = 0; j < D2; j++) {
        float hg = hg_sum[g * D2 + j] * inv;
        float z = bp[j];
        for (int k = 0; k < DSELF; k++) z += sf[k] * Wp[k * D2 + j];
        float gate = 1.f / (1.f + expf(-hg * z));
        f[j] = gate * hg + (1.f - gate) * z;
    }
    float r[10];
    for (int j = 0; j < 10; j++) {
        float a = bf1[j];
        for (int k = 0; k < D2; k++) a += f[k] * Wf1[k * 10 + j];
        r[j] = fmaxf(a, 0.f);
    }
    float o = bf2[0];
    for (int k = 0; k < 10; k++) o += r[k] * Wf2[k];
    out[g] = o;
}

// ---------------- launch ----------------

extern "C" void kernel_launch(void* const* d_in, const int* in_sizes, int n_in,
                              void* d_out, int out_size, void* d_ws, size_t ws_size,
                              hipStream_t stream) {
    const float* feat      = (const float*)d_in[0];
    const int*   src       = (const int*)d_in[1];
    const int*   dst       = (const int*)d_in[2];
    const int*   gid       = (const int*)d_in[3];
    const float* self_feat = (const float*)d_in[4];
    const float* W1  = (const float*)d_in[5];
    const float* b1  = (const float*)d_in[6];
    const float* W2  = (const float*)d_in[7];
    const float* b2  = (const float*)d_in[8];
    const float* Wp  = (const float*)d_in[9];
    const float* bp  = (const float*)d_in[10];
    const float* Wf1 = (const float*)d_in[11];
    const float* bf1 = (const float*)d_in[12];
    const float* Wf2 = (const float*)d_in[13];
    const float* bf2 = (const float*)d_in[14];
    float* out = (float*)d_out;

    char* ws = (char*)d_ws;
    // workspace layout (16B-aligned offsets)
    int*   deg       = (int*)(ws + 0);          // 50000 ints
    int*   cursor    = (int*)(ws + 200704);     // 50000 ints
    int*   row_start = (int*)(ws + 401408);     // 50001 ints
    float* hg_sum    = (float*)(ws + 602112);   // 256*20 floats
    float* cnt       = (float*)(ws + 622592);   // 256 floats
    int*   csr       = (int*)(ws + 623616);     // 1.6M ints
    float* bufA      = (float*)(ws + 7023616);  // y1 [50000*100], then y2 [50000*20]
    float* bufB      = (float*)(ws + 27023616); // h1 [50000*100]
    // total: 47,023,616 bytes

    // ws is poisoned 0xAA before every launch: zero what must start at 0
    hipMemsetAsync(deg, 0, 401408, stream);     // deg + cursor
    hipMemsetAsync(hg_sum, 0, 21504, stream);   // hg_sum + cnt

    k_deg<<<6250, 256, 0, stream>>>(dst, deg);
    k_scan<<<1, 1024, 0, stream>>>(deg, row_start);
    k_fill<<<6250, 256, 0, stream>>>(src, dst, row_start, cursor, csr);

    k_gemm1<<<6250, 256, 0, stream>>>(feat, W1, bufA);
    k_agg1<<<25000, 256, 0, stream>>>(bufA, csr, row_start, b1, bufB);
    k_gemm2<<<6250, 256, 0, stream>>>(bufB, W2, bufA);
    k_agg2<<<6250, 256, 0, stream>>>(bufA, csr, row_start, b2, gid, hg_sum, cnt);
    k_final<<<1, 256, 0, stream>>>(hg_sum, cnt, self_feat, Wp, bp, Wf1, bf1, Wf2, bf2, out);
}

// Round 2
// 716.918 us; speedup vs baseline: 1.3621x; 1.3621x over previous
//
#include <hip/hip_runtime.h>
#include <hip/hip_bf16.h>
#include <math.h>

#define NN 50000
#define NE 1600000
#define NG 256
#define DIN 128
#define D1 100
#define D1P 104   // bf16 row stride for y1 (13 groups of 8, 208 B, 16B-aligned)
#define D2 20
#define DSELF 64

static __device__ __forceinline__ unsigned short f2bf(float x) {
    __hip_bfloat16 h = __float2bfloat16(x);
    unsigned short u;
    __builtin_memcpy(&u, &h, 2);
    return u;
}
static __device__ __forceinline__ float bflo(unsigned u) {
    union { unsigned i; float f; } c; c.i = u << 16; return c.f;
}
static __device__ __forceinline__ float bfhi(unsigned u) {
    union { unsigned i; float f; } c; c.i = u & 0xffff0000u; return c.f;
}

// ---------------- CSR build ----------------

__global__ void k_deg(const int* __restrict__ dst, int* __restrict__ deg) {
    int i = blockIdx.x * 256 + threadIdx.x;
    if (i < NE) atomicAdd(&deg[dst[i]], 1);
}

// single-block scan: each thread owns 49 contiguous elements, serial sum +
// one 1024-wide LDS scan (replaces the per-tile 20-barrier Hillis-Steele).
#define SCAN_T 1024
#define CHUNK 49
__global__ void k_scan(const int* __restrict__ deg, int* __restrict__ row_start) {
    __shared__ int psum[SCAN_T];
    int tid = threadIdx.x;
    int start = tid * CHUNK;
    int s = 0;
    for (int i = 0; i < CHUNK; i++) {
        int idx = start + i;
        s += (idx < NN) ? deg[idx] : 0;
    }
    psum[tid] = s;
    __syncthreads();
    for (int off = 1; off < SCAN_T; off <<= 1) {
        int t = (tid >= off) ? psum[tid - off] : 0;
        __syncthreads();
        psum[tid] += t;
        __syncthreads();
    }
    int run = (tid > 0) ? psum[tid - 1] : 0;
    for (int i = 0; i < CHUNK; i++) {
        int idx = start + i;
        if (idx < NN) { row_start[idx] = run; run += deg[idx]; }
    }
    if (tid == SCAN_T - 1) row_start[NN] = psum[SCAN_T - 1];
}

__global__ void k_fill(const int* __restrict__ src, const int* __restrict__ dst,
                       const int* __restrict__ row_start, int* __restrict__ cursor,
                       int* __restrict__ csr) {
    int e = blockIdx.x * 256 + threadIdx.x;
    if (e < NE) {
        int d = dst[e];
        int p = atomicAdd(&cursor[d], 1);
        csr[row_start[d] + p] = src[e];
    }
}

// ---------------- layer 1 GEMM: y1[n][j] = feat[n,:] @ W1[:,j], bf16 out ----------------

__global__ __launch_bounds__(256) void k_gemm1(const float* __restrict__ feat,
        const float* __restrict__ W1, unsigned short* __restrict__ y1) {
    __shared__ float sf[8 * DIN];
    int tid = threadIdx.x;
    int n0 = blockIdx.x * 8;
    // stage 8 feat rows (1024 floats) coalesced
    *reinterpret_cast<float4*>(sf + tid * 4) =
        *reinterpret_cast<const float4*>(feat + (size_t)n0 * DIN + tid * 4);
    __syncthreads();
    int r = tid >> 5, jg = tid & 31;   // jg: 4-wide column group, 25 active
    if (jg >= 25) return;
    const float* frow = sf + r * DIN;
    const float* w = W1 + jg * 4;
    float4 acc = make_float4(0.f, 0.f, 0.f, 0.f);
#pragma unroll 8
    for (int k = 0; k < DIN; k++) {
        float f = frow[k];
        float4 wv = *reinterpret_cast<const float4*>(w + (size_t)k * D1);
        acc.x += f * wv.x; acc.y += f * wv.y; acc.z += f * wv.z; acc.w += f * wv.w;
    }
    int n = n0 + r;
    ushort4 st;
    st.x = f2bf(acc.x); st.y = f2bf(acc.y); st.z = f2bf(acc.z); st.w = f2bf(acc.w);
    *reinterpret_cast<ushort4*>(y1 + (size_t)n * D1P + jg * 4) = st;
    if (jg == 24) {  // zero padding dims 100..103
        ushort4 z; z.x = z.y = z.z = z.w = 0;
        *reinterpret_cast<ushort4*>(y1 + (size_t)n * D1P + 100) = z;
    }
}

// ---------------- layer 1 aggregation: wave per node, 4 edges in flight ----------------

__global__ __launch_bounds__(256) void k_agg1(const unsigned short* __restrict__ y1,
        const int* __restrict__ csr, const int* __restrict__ row_start,
        const float* __restrict__ b1, float* __restrict__ h1) {
    int tid = threadIdx.x;
    int n = blockIdx.x * 4 + (tid >> 6);
    int lane = tid & 63;
    int esub = lane >> 4;   // 0..3: which edge of the 4-in-flight group
    int dg = lane & 15;     // 0..15: 8-dim group, active dg<13
    int s = row_start[n], e = row_start[n + 1];
    float acc[8] = {0.f, 0.f, 0.f, 0.f, 0.f, 0.f, 0.f, 0.f};
    if (dg < 13) {
        int i = s + esub;
        int sn = (i < e) ? csr[i] : 0;
        while (i < e) {
            int ni = i + 4;
            int nsn = (ni < e) ? csr[ni] : 0;   // prefetch next index
            const uint4 pk = *reinterpret_cast<const uint4*>(y1 + (size_t)sn * D1P + dg * 8);
            acc[0] += bflo(pk.x); acc[1] += bfhi(pk.x);
            acc[2] += bflo(pk.y); acc[3] += bfhi(pk.y);
            acc[4] += bflo(pk.z); acc[5] += bfhi(pk.z);
            acc[6] += bflo(pk.w); acc[7] += bfhi(pk.w);
            sn = nsn; i = ni;
        }
    }
#pragma unroll
    for (int j = 0; j < 8; j++) {
        acc[j] += __shfl_xor(acc[j], 16, 64);
        acc[j] += __shfl_xor(acc[j], 32, 64);
    }
    if (esub == 0 && dg < 13) {
        int degn = e - s;
        float res[8];
        if (degn > 0) {
            float inv = 1.f / (float)degn;
#pragma unroll
            for (int j = 0; j < 8; j++) res[j] = acc[j] * inv;
        } else {
            const uint4 pk = *reinterpret_cast<const uint4*>(y1 + (size_t)n * D1P + dg * 8);
            res[0] = bflo(pk.x); res[1] = bfhi(pk.x);
            res[2] = bflo(pk.y); res[3] = bfhi(pk.y);
            res[4] = bflo(pk.z); res[5] = bfhi(pk.z);
            res[6] = bflo(pk.w); res[7] = bfhi(pk.w);
        }
        int d0 = dg * 8;
        float* orow = h1 + (size_t)n * D1;
#pragma unroll
        for (int j = 0; j < 4; j++) res[j] = fmaxf(res[j] + b1[d0 + j], 0.f);
        *reinterpret_cast<float4*>(orow + d0) = make_float4(res[0], res[1], res[2], res[3]);
        if (dg < 12) {
#pragma unroll
            for (int j = 4; j < 8; j++) res[j] = fmaxf(res[j] + b1[d0 + j], 0.f);
            *reinterpret_cast<float4*>(orow + d0 + 4) = make_float4(res[4], res[5], res[6], res[7]);
        }
    }
}

// ---------------- layer 2 GEMM: y2[n][j] = h1[n,:] @ W2[:,j] ----------------

__global__ __launch_bounds__(256) void k_gemm2(const float* __restrict__ h1,
        const float* __restrict__ W2, float* __restrict__ y2) {
    __shared__ float sh[8 * D1];
    int tid = threadIdx.x;
    int n0 = blockIdx.x * 8;
    if (tid < 200)  // 8 rows * 100 floats = 800 = 200 float4 (rows are contiguous)
        *reinterpret_cast<float4*>(sh + tid * 4) =
            *reinterpret_cast<const float4*>(h1 + (size_t)n0 * D1 + tid * 4);
    __syncthreads();
    int r = tid >> 5, j = tid & 31;
    if (j >= D2) return;
    const float* hr = sh + r * D1;
    float acc = 0.f;
#pragma unroll 10
    for (int k = 0; k < D1; k++) acc += hr[k] * W2[k * D2 + j];
    y2[(size_t)(n0 + r) * D2 + j] = acc;
}

// ---------------- layer 2 aggregation + fused graph pooling ----------------

__global__ __launch_bounds__(256) void k_agg2(const float* __restrict__ y2,
        const int* __restrict__ csr, const int* __restrict__ row_start,
        const float* __restrict__ b2, const int* __restrict__ gid,
        float* __restrict__ hg_sum, float* __restrict__ cnt) {
    int tid = threadIdx.x;
    int n = blockIdx.x * 4 + (tid >> 6);
    int lane = tid & 63;
    int esub = lane >> 3;   // 0..7: 8 edges in flight
    int dg = lane & 7;      // 4-dim group, active dg<5
    int s = row_start[n], e = row_start[n + 1];
    float a0 = 0.f, a1 = 0.f, a2 = 0.f, a3 = 0.f;
    if (dg < 5) {
        int i = s + esub;
        int sn = (i < e) ? csr[i] : 0;
        while (i < e) {
            int ni = i + 8;
            int nsn = (ni < e) ? csr[ni] : 0;
            float4 v = *reinterpret_cast<const float4*>(y2 + (size_t)sn * D2 + dg * 4);
            a0 += v.x; a1 += v.y; a2 += v.z; a3 += v.w;
            sn = nsn; i = ni;
        }
    }
    a0 += __shfl_xor(a0, 8, 64); a0 += __shfl_xor(a0, 16, 64); a0 += __shfl_xor(a0, 32, 64);
    a1 += __shfl_xor(a1, 8, 64); a1 += __shfl_xor(a1, 16, 64); a1 += __shfl_xor(a1, 32, 64);
    a2 += __shfl_xor(a2, 8, 64); a2 += __shfl_xor(a2, 16, 64); a2 += __shfl_xor(a2, 32, 64);
    a3 += __shfl_xor(a3, 8, 64); a3 += __shfl_xor(a3, 16, 64); a3 += __shfl_xor(a3, 32, 64);
    int g = gid[n];
    if (esub == 0 && dg < 5) {
        int degn = e - s;
        float r0, r1, r2, r3;
        if (degn > 0) {
            float inv = 1.f / (float)degn;
            r0 = a0 * inv; r1 = a1 * inv; r2 = a2 * inv; r3 = a3 * inv;
        } else {
            float4 v = *reinterpret_cast<const float4*>(y2 + (size_t)n * D2 + dg * 4);
            r0 = v.x; r1 = v.y; r2 = v.z; r3 = v.w;
        }
        int d0 = dg * 4;
        r0 = fmaxf(r0 + b2[d0 + 0], 0.f);
        r1 = fmaxf(r1 + b2[d0 + 1], 0.f);
        r2 = fmaxf(r2 + b2[d0 + 2], 0.f);
        r3 = fmaxf(r3 + b2[d0 + 3], 0.f);
        float* hs = hg_sum + (size_t)g * D2 + d0;
        atomicAdd(hs + 0, r0); atomicAdd(hs + 1, r1);
        atomicAdd(hs + 2, r2); atomicAdd(hs + 3, r3);
    }
    if (lane == 0) atomicAdd(&cnt[g], 1.f);
}

// ---------------- final: pool finalize + bilinear gate + MLP ----------------

__global__ void k_final(const float* __restrict__ hg_sum, const float* __restrict__ cnt,
                        const float* __restrict__ self_feat,
                        const float* __restrict__ Wp, const float* __restrict__ bp,
                        const float* __restrict__ Wf1, const float* __restrict__ bf1,
                        const float* __restrict__ Wf2, const float* __restrict__ bf2,
                        float* __restrict__ out) {
    int g = blockIdx.x * blockDim.x + threadIdx.x;
    if (g >= NG) return;
    float inv = 1.f / fmaxf(cnt[g], 1.f);
    const float* sf = self_feat + g * DSELF;
    float f[D2];
    for (int j = 0; j < D2; j++) {
        float hg = hg_sum[g * D2 + j] * inv;
        float z = bp[j];
        for (int k = 0; k < DSELF; k++) z += sf[k] * Wp[k * D2 + j];
        float gate = 1.f / (1.f + expf(-hg * z));
        f[j] = gate * hg + (1.f - gate) * z;
    }
    float r[10];
    for (int j = 0; j < 10; j++) {
        float a = bf1[j];
        for (int k = 0; k < D2; k++) a += f[k] * Wf1[k * 10 + j];
        r[j] = fmaxf(a, 0.f);
    }
    float o = bf2[0];
    for (int k = 0; k < 10; k++) o += r[k] * Wf2[k];
    out[g] = o;
}

// ---------------- launch ----------------

extern "C" void kernel_launch(void* const* d_in, const int* in_sizes, int n_in,
                              void* d_out, int out_size, void* d_ws, size_t ws_size,
                              hipStream_t stream) {
    const float* feat      = (const float*)d_in[0];
    const int*   src       = (const int*)d_in[1];
    const int*   dst       = (const int*)d_in[2];
    const int*   gid       = (const int*)d_in[3];
    const float* self_feat = (const float*)d_in[4];
    const float* W1  = (const float*)d_in[5];
    const float* b1  = (const float*)d_in[6];
    const float* W2  = (const float*)d_in[7];
    const float* b2  = (const float*)d_in[8];
    const float* Wp  = (const float*)d_in[9];
    const float* bp  = (const float*)d_in[10];
    const float* Wf1 = (const float*)d_in[11];
    const float* bf1 = (const float*)d_in[12];
    const float* Wf2 = (const float*)d_in[13];
    const float* bf2 = (const float*)d_in[14];
    float* out = (float*)d_out;

    char* ws = (char*)d_ws;
    int*            deg       = (int*)(ws + 0);          // 50000 ints
    int*            cursor    = (int*)(ws + 200704);     // 50000 ints
    int*            row_start = (int*)(ws + 401408);     // 50001 ints
    float*          hg_sum    = (float*)(ws + 602112);   // 256*20
    float*          cnt       = (float*)(ws + 622592);   // 256
    int*            csr       = (int*)(ws + 623616);     // 1.6M ints -> ends 7023616
    unsigned short* y1bf      = (unsigned short*)(ws + 7023616);  // 50000*104 bf16 -> ends 17423616
    float*          h1        = (float*)(ws + 17423616); // 50000*100 -> ends 37423616
    float*          y2        = (float*)(ws + 37423616); // 50000*20  -> ends 41423616

    hipMemsetAsync(deg, 0, 401408, stream);     // deg + cursor
    hipMemsetAsync(hg_sum, 0, 21504, stream);   // hg_sum + cnt

    k_deg<<<6250, 256, 0, stream>>>(dst, deg);
    k_scan<<<1, 1024, 0, stream>>>(deg, row_start);
    k_fill<<<6250, 256, 0, stream>>>(src, dst, row_start, cursor, csr);

    k_gemm1<<<6250, 256, 0, stream>>>(feat, W1, y1bf);
    k_agg1<<<12500, 256, 0, stream>>>(y1bf, csr, row_start, b1, h1);
    k_gemm2<<<6250, 256, 0, stream>>>(h1, W2, y2);
    k_agg2<<<12500, 256, 0, stream>>>(y2, csr, row_start, b2, gid, hg_sum, cnt);
    k_final<<<1, 256, 0, stream>>>(hg_sum, cnt, self_feat, Wp, bp, Wf1, bf1, Wf2, bf2, out);
}

// Round 3
// 556.850 us; speedup vs baseline: 1.7537x; 1.2875x over previous
//
#include <hip/hip_runtime.h>
#include <hip/hip_bf16.h>
#include <math.h>

#define NN 50000
#define NE 1600000
#define NG 256
#define DIN 128
#define D1 100
#define D1P 104   // bf16 row stride for y1 (13 groups of 8, 208 B, 16B-aligned)
#define D2 20
#define DSELF 64

static __device__ __forceinline__ unsigned short f2bf(float x) {
    __hip_bfloat16 h = __float2bfloat16(x);
    unsigned short u;
    __builtin_memcpy(&u, &h, 2);
    return u;
}
static __device__ __forceinline__ float bflo(unsigned u) {
    union { unsigned i; float f; } c; c.i = u << 16; return c.f;
}
static __device__ __forceinline__ float bfhi(unsigned u) {
    union { unsigned i; float f; } c; c.i = u & 0xffff0000u; return c.f;
}

// ---------------- CSR build ----------------

__global__ void k_deg(const int* __restrict__ dst, int* __restrict__ deg) {
    int i = blockIdx.x * 256 + threadIdx.x;
    if (i < NE) atomicAdd(&deg[dst[i]], 1);
}

// graph_start[g] from sorted gid (covers every g in [0, NG], incl. empty graphs)
__global__ void k_mark(const int* __restrict__ gid, int* __restrict__ graph_start) {
    int i = blockIdx.x * 256 + threadIdx.x;
    if (i >= NN) return;
    int g = gid[i];
    if (i == 0) {
        for (int x = 0; x <= g; x++) graph_start[x] = 0;
    } else {
        int p = gid[i - 1];
        if (p != g) for (int x = p + 1; x <= g; x++) graph_start[x] = i;
    }
    if (i == NN - 1) {
        for (int x = g + 1; x <= NG; x++) graph_start[x] = NN;
    }
}

// single-block scan: each thread owns 49 contiguous elements
#define SCAN_T 1024
#define CHUNK 49
__global__ void k_scan(const int* __restrict__ deg, int* __restrict__ row_start) {
    __shared__ int psum[SCAN_T];
    int tid = threadIdx.x;
    int start = tid * CHUNK;
    int s = 0;
    for (int i = 0; i < CHUNK; i++) {
        int idx = start + i;
        s += (idx < NN) ? deg[idx] : 0;
    }
    psum[tid] = s;
    __syncthreads();
    for (int off = 1; off < SCAN_T; off <<= 1) {
        int t = (tid >= off) ? psum[tid - off] : 0;
        __syncthreads();
        psum[tid] += t;
        __syncthreads();
    }
    int run = (tid > 0) ? psum[tid - 1] : 0;
    for (int i = 0; i < CHUNK; i++) {
        int idx = start + i;
        if (idx < NN) { row_start[idx] = run; run += deg[idx]; }
    }
    if (tid == SCAN_T - 1) row_start[NN] = psum[SCAN_T - 1];
}

__global__ void k_fill(const int* __restrict__ src, const int* __restrict__ dst,
                       const int* __restrict__ row_start, int* __restrict__ cursor,
                       int* __restrict__ csr) {
    int e = blockIdx.x * 256 + threadIdx.x;
    if (e < NE) {
        int d = dst[e];
        int p = atomicAdd(&cursor[d], 1);
        csr[row_start[d] + p] = src[e];
    }
}

// ---------------- layer 1 GEMM: y1 = feat @ W1 (bf16 out, no bias) ----------------

__global__ __launch_bounds__(256) void k_gemm1(const float* __restrict__ feat,
        const float* __restrict__ W1, unsigned short* __restrict__ y1) {
    __shared__ float sf[8 * DIN];
    int tid = threadIdx.x;
    int n0 = blockIdx.x * 8;
    *reinterpret_cast<float4*>(sf + tid * 4) =
        *reinterpret_cast<const float4*>(feat + (size_t)n0 * DIN + tid * 4);
    __syncthreads();
    int r = tid >> 5, jg = tid & 31;
    if (jg >= 25) return;
    const float* frow = sf + r * DIN;
    const float* w = W1 + jg * 4;
    float4 acc = make_float4(0.f, 0.f, 0.f, 0.f);
#pragma unroll 8
    for (int k = 0; k < DIN; k++) {
        float f = frow[k];
        float4 wv = *reinterpret_cast<const float4*>(w + (size_t)k * D1);
        acc.x += f * wv.x; acc.y += f * wv.y; acc.z += f * wv.z; acc.w += f * wv.w;
    }
    int n = n0 + r;
    ushort4 st;
    st.x = f2bf(acc.x); st.y = f2bf(acc.y); st.z = f2bf(acc.z); st.w = f2bf(acc.w);
    *reinterpret_cast<ushort4*>(y1 + (size_t)n * D1P + jg * 4) = st;
    if (jg == 24) {
        ushort4 z; z.x = z.y = z.z = z.w = 0;
        *reinterpret_cast<ushort4*>(y1 + (size_t)n * D1P + 100) = z;
    }
}

// ---------------- layer 1 aggregation: wave/node, csr preload + shfl broadcast ----------------

__global__ __launch_bounds__(256) void k_agg1(const unsigned short* __restrict__ y1,
        const int* __restrict__ csr, const int* __restrict__ row_start,
        const float* __restrict__ b1, float* __restrict__ h1) {
    int tid = threadIdx.x;
    int n = blockIdx.x * 4 + (tid >> 6);
    int lane = tid & 63;
    int esub = lane >> 4;   // 0..3
    int dg = lane & 15;     // 0..15, active < 13
    int s = row_start[n], e = row_start[n + 1];
    float acc[8] = {0.f, 0.f, 0.f, 0.f, 0.f, 0.f, 0.f, 0.f};
    for (int base = s; base < e; base += 64) {
        int cn = e - base; if (cn > 64) cn = 64;
        int vidx = (lane < cn) ? csr[base + lane] : 0;  // one coalesced index load
        for (int r = 0; r < cn; r += 8) {
            int sA = r + esub, sB = r + esub + 4;
            int iA = __shfl(vidx, sA, 64);
            int iB = __shfl(vidx, sB, 64);
            if (dg < 13) {
                if (sA < cn) {
                    const uint4 pk = *reinterpret_cast<const uint4*>(y1 + (size_t)iA * D1P + dg * 8);
                    acc[0] += bflo(pk.x); acc[1] += bfhi(pk.x);
                    acc[2] += bflo(pk.y); acc[3] += bfhi(pk.y);
                    acc[4] += bflo(pk.z); acc[5] += bfhi(pk.z);
                    acc[6] += bflo(pk.w); acc[7] += bfhi(pk.w);
                }
                if (sB < cn) {
                    const uint4 pk = *reinterpret_cast<const uint4*>(y1 + (size_t)iB * D1P + dg * 8);
                    acc[0] += bflo(pk.x); acc[1] += bfhi(pk.x);
                    acc[2] += bflo(pk.y); acc[3] += bfhi(pk.y);
                    acc[4] += bflo(pk.z); acc[5] += bfhi(pk.z);
                    acc[6] += bflo(pk.w); acc[7] += bfhi(pk.w);
                }
            }
        }
    }
#pragma unroll
    for (int j = 0; j < 8; j++) {
        acc[j] += __shfl_xor(acc[j], 16, 64);
        acc[j] += __shfl_xor(acc[j], 32, 64);
    }
    if (esub == 0 && dg < 13) {
        int degn = e - s;
        float res[8];
        if (degn > 0) {
            float inv = 1.f / (float)degn;
#pragma unroll
            for (int j = 0; j < 8; j++) res[j] = acc[j] * inv;
        } else {
            const uint4 pk = *reinterpret_cast<const uint4*>(y1 + (size_t)n * D1P + dg * 8);
            res[0] = bflo(pk.x); res[1] = bfhi(pk.x);
            res[2] = bflo(pk.y); res[3] = bfhi(pk.y);
            res[4] = bflo(pk.z); res[5] = bfhi(pk.z);
            res[6] = bflo(pk.w); res[7] = bfhi(pk.w);
        }
        int d0 = dg * 8;
        float* orow = h1 + (size_t)n * D1;
#pragma unroll
        for (int j = 0; j < 4; j++) res[j] = fmaxf(res[j] + b1[d0 + j], 0.f);
        *reinterpret_cast<float4*>(orow + d0) = make_float4(res[0], res[1], res[2], res[3]);
        if (dg < 12) {
#pragma unroll
            for (int j = 4; j < 8; j++) res[j] = fmaxf(res[j] + b1[d0 + j], 0.f);
            *reinterpret_cast<float4*>(orow + d0 + 4) = make_float4(res[4], res[5], res[6], res[7]);
        }
    }
}

// ---------------- layer 2 GEMM: y2 = h1 @ W2 (no bias) ----------------

__global__ __launch_bounds__(256) void k_gemm2(const float* __restrict__ h1,
        const float* __restrict__ W2, float* __restrict__ y2) {
    __shared__ float sh[8 * D1];
    int tid = threadIdx.x;
    int n0 = blockIdx.x * 8;
    if (tid < 200)
        *reinterpret_cast<float4*>(sh + tid * 4) =
            *reinterpret_cast<const float4*>(h1 + (size_t)n0 * D1 + tid * 4);
    __syncthreads();
    int r = tid >> 5, j = tid & 31;
    if (j >= D2) return;
    const float* hr = sh + r * D1;
    float acc = 0.f;
#pragma unroll 10
    for (int k = 0; k < D1; k++) acc += hr[k] * W2[k * D2 + j];
    y2[(size_t)(n0 + r) * D2 + j] = acc;
}

// ---------------- layer 2 aggregation: writes h2 (no atomics) ----------------

__global__ __launch_bounds__(256) void k_agg2(const float* __restrict__ y2,
        const int* __restrict__ csr, const int* __restrict__ row_start,
        const float* __restrict__ b2, float* __restrict__ h2) {
    int tid = threadIdx.x;
    int n = blockIdx.x * 4 + (tid >> 6);
    int lane = tid & 63;
    int esub = lane >> 3;   // 0..7
    int dg = lane & 7;      // active < 5
    int s = row_start[n], e = row_start[n + 1];
    float a0 = 0.f, a1 = 0.f, a2 = 0.f, a3 = 0.f;
    for (int base = s; base < e; base += 64) {
        int cn = e - base; if (cn > 64) cn = 64;
        int vidx = (lane < cn) ? csr[base + lane] : 0;
        for (int r = 0; r < cn; r += 16) {
            int sA = r + esub, sB = r + esub + 8;
            int iA = __shfl(vidx, sA, 64);
            int iB = __shfl(vidx, sB, 64);
            if (dg < 5) {
                if (sA < cn) {
                    float4 v = *reinterpret_cast<const float4*>(y2 + (size_t)iA * D2 + dg * 4);
                    a0 += v.x; a1 += v.y; a2 += v.z; a3 += v.w;
                }
                if (sB < cn) {
                    float4 v = *reinterpret_cast<const float4*>(y2 + (size_t)iB * D2 + dg * 4);
                    a0 += v.x; a1 += v.y; a2 += v.z; a3 += v.w;
                }
            }
        }
    }
    a0 += __shfl_xor(a0, 8, 64); a0 += __shfl_xor(a0, 16, 64); a0 += __shfl_xor(a0, 32, 64);
    a1 += __shfl_xor(a1, 8, 64); a1 += __shfl_xor(a1, 16, 64); a1 += __shfl_xor(a1, 32, 64);
    a2 += __shfl_xor(a2, 8, 64); a2 += __shfl_xor(a2, 16, 64); a2 += __shfl_xor(a2, 32, 64);
    a3 += __shfl_xor(a3, 8, 64); a3 += __shfl_xor(a3, 16, 64); a3 += __shfl_xor(a3, 32, 64);
    if (esub == 0 && dg < 5) {
        int degn = e - s;
        float r0, r1, r2, r3;
        if (degn > 0) {
            float inv = 1.f / (float)degn;
            r0 = a0 * inv; r1 = a1 * inv; r2 = a2 * inv; r3 = a3 * inv;
        } else {
            float4 v = *reinterpret_cast<const float4*>(y2 + (size_t)n * D2 + dg * 4);
            r0 = v.x; r1 = v.y; r2 = v.z; r3 = v.w;
        }
        int d0 = dg * 4;
        r0 = fmaxf(r0 + b2[d0 + 0], 0.f);
        r1 = fmaxf(r1 + b2[d0 + 1], 0.f);
        r2 = fmaxf(r2 + b2[d0 + 2], 0.f);
        r3 = fmaxf(r3 + b2[d0 + 3], 0.f);
        *reinterpret_cast<float4*>(h2 + (size_t)n * D2 + d0) = make_float4(r0, r1, r2, r3);
    }
}

// ---------------- pooling + gate + MLP, one block per graph, no atomics ----------------

__global__ __launch_bounds__(256) void k_pool(const float* __restrict__ h2,
        const int* __restrict__ graph_start, const float* __restrict__ self_feat,
        const float* __restrict__ Wp, const float* __restrict__ bp,
        const float* __restrict__ Wf1, const float* __restrict__ bf1,
        const float* __restrict__ Wf2, const float* __restrict__ bf2,
        float* __restrict__ out) {
    __shared__ float red[8][D2];
    __shared__ float fbuf[D2];
    __shared__ float rbuf[10];
    int g = blockIdx.x;
    int start = graph_start[g], end = graph_start[g + 1];
    int tid = threadIdx.x;
    int j = tid & 31;
    int rs = tid >> 5;  // 8 row slots
    float a = 0.f;
    if (j < D2)
        for (int i = start + rs; i < end; i += 8) a += h2[(size_t)i * D2 + j];
    if (j < D2) red[rs][j] = a;
    __syncthreads();
    if (tid < D2) {
        float sum = 0.f;
#pragma unroll
        for (int k = 0; k < 8; k++) sum += red[k][tid];
        float m = (float)(end - start);
        float hg = sum / fmaxf(m, 1.f);
        float z = bp[tid];
        const float* sf = self_feat + g * DSELF;
        for (int k = 0; k < DSELF; k++) z += sf[k] * Wp[k * D2 + tid];
        float gate = 1.f / (1.f + expf(-hg * z));
        fbuf[tid] = gate * hg + (1.f - gate) * z;
    }
    __syncthreads();
    if (tid < 10) {
        float a2 = bf1[tid];
        for (int k = 0; k < D2; k++) a2 += fbuf[k] * Wf1[k * 10 + tid];
        rbuf[tid] = fmaxf(a2, 0.f);
    }
    __syncthreads();
    if (tid == 0) {
        float o = bf2[0];
        for (int k = 0; k < 10; k++) o += rbuf[k] * Wf2[k];
        out[g] = o;
    }
}

// ---------------- launch ----------------

extern "C" void kernel_launch(void* const* d_in, const int* in_sizes, int n_in,
                              void* d_out, int out_size, void* d_ws, size_t ws_size,
                              hipStream_t stream) {
    const float* feat      = (const float*)d_in[0];
    const int*   src       = (const int*)d_in[1];
    const int*   dst       = (const int*)d_in[2];
    const int*   gid       = (const int*)d_in[3];
    const float* self_feat = (const float*)d_in[4];
    const float* W1  = (const float*)d_in[5];
    const float* b1  = (const float*)d_in[6];
    const float* W2  = (const float*)d_in[7];
    const float* b2  = (const float*)d_in[8];
    const float* Wp  = (const float*)d_in[9];
    const float* bp  = (const float*)d_in[10];
    const float* Wf1 = (const float*)d_in[11];
    const float* bf1 = (const float*)d_in[12];
    const float* Wf2 = (const float*)d_in[13];
    const float* bf2 = (const float*)d_in[14];
    float* out = (float*)d_out;

    char* ws = (char*)d_ws;
    int*            deg         = (int*)(ws + 0);          // 50000 ints
    int*            cursor      = (int*)(ws + 200704);     // 50000 ints
    int*            row_start   = (int*)(ws + 401408);     // 50001 ints
    int*            graph_start = (int*)(ws + 602112);     // 257 ints
    int*            csr         = (int*)(ws + 623616);     // 1.6M ints  -> ends 7023616
    unsigned short* y1bf        = (unsigned short*)(ws + 7023616);  // 50000*104 bf16 -> ends 17423616
    float*          h2          = (float*)(ws + 7023616);  // reuses y1bf space after agg1 (4 MB)
    float*          h1          = (float*)(ws + 17423616); // 50000*100 -> ends 37423616
    float*          y2          = (float*)(ws + 37423616); // 50000*20  -> ends 41423616

    hipMemsetAsync(deg, 0, 401408, stream);  // deg + cursor

    k_deg<<<6250, 256, 0, stream>>>(dst, deg);
    k_mark<<<196, 256, 0, stream>>>(gid, graph_start);
    k_scan<<<1, 1024, 0, stream>>>(deg, row_start);
    k_fill<<<6250, 256, 0, stream>>>(src, dst, row_start, cursor, csr);

    k_gemm1<<<6250, 256, 0, stream>>>(feat, W1, y1bf);
    k_agg1<<<12500, 256, 0, stream>>>(y1bf, csr, row_start, b1, h1);
    k_gemm2<<<6250, 256, 0, stream>>>(h1, W2, y2);
    k_agg2<<<12500, 256, 0, stream>>>(y2, csr, row_start, b2, h2);   // h2 overwrites y1bf space (y1 dead)
    k_pool<<<NG, 256, 0, stream>>>(h2, graph_start, self_feat, Wp, bp, Wf1, bf1, Wf2, bf2, out);
}